// Round 11
// baseline (148.839 us; speedup 1.0000x reference)
//
#include <hip/hip_runtime.h>
#include <hip/hip_bf16.h>
#include <stdint.h>

#define MB_ 8192
#define FD  512
#define OD  512
#define KD  8704     // F*16 + F (basis + residual)
#define KBASIS 8192
// bt2 tiled geometry: chunk(ct, ks, o) ; ks in [0,1088), o in [0,128), 16B chunks
#define BT_KS   1088
#define BT_CHUNKS_PER_CT (BT_KS * 128)          // 139264
#define BT_BYTES_PER_CT  (BT_CHUNKS_PER_CT * 16) // 2228224

typedef __attribute__((ext_vector_type(4))) float f32x4;
typedef __attribute__((ext_vector_type(8))) short bf16x8;
typedef __attribute__((ext_vector_type(4))) unsigned int u32x4;
typedef __attribute__((ext_vector_type(2))) unsigned int u32x2;

__device__ __forceinline__ void gload_lds16(const void* g, void* l) {
  __builtin_amdgcn_global_load_lds((const __attribute__((address_space(1))) void*)g,
                                   (__attribute__((address_space(3))) void*)l,
                                   16, 0, 0);
}

__device__ __forceinline__ uint32_t bf_rtn(float f) {
  uint32_t u = __float_as_uint(f);
  return (u + 0x7fffu + ((u >> 16) & 1u)) >> 16;
}

// packed bf16 pair (a in low 16, b in high 16) via HW v_cvt_pk_bf16_f32
__device__ __forceinline__ uint32_t pk(float a, float b) {
  uint32_t r;
  asm("v_cvt_pk_bf16_f32 %0, %1, %2" : "=v"(r) : "v"(a), "v"(b));
  return r;
}

// ---------------- phase 1: t = tanh(x) fp32, xbf = bf16(x) ----------------
__global__ __launch_bounds__(256) void k_tanh(const float* __restrict__ x,
                                              float* __restrict__ t,
                                              uint16_t* __restrict__ xbf) {
  int i = blockIdx.x * 256 + threadIdx.x;   // 0 .. 2^20-1, 4 elems each
  f32x4 v = ((const f32x4*)x)[i];
  f32x4 tv;
  tv[0] = tanhf(v[0]); tv[1] = tanhf(v[1]);
  tv[2] = tanhf(v[2]); tv[3] = tanhf(v[3]);
  ((f32x4*)t)[i] = tv;
  u32x2 p;
  p[0] = pk(v[0], v[1]);
  p[1] = pk(v[2], v[3]);
  ((u32x2*)xbf)[i] = p;
}

// ---------------- phase 2: bt2 tiled repack (PROVEN rounds 4..10) -----------
// chunk(ct, ks, o) holds bf16 Bt[ct*128+o][ks*8 .. +8)
// where Bt[o][i*16+n] = coeffs[i,o,n] ; Bt[o][8192+i] = bw[i,o]
__global__ __launch_bounds__(256) void k_bt(const float* __restrict__ coeffs,
                                            const float* __restrict__ bw,
                                            uint16_t* __restrict__ bt2,
                                            float* __restrict__ out) {
  int tid = blockIdx.x * 256 + threadIdx.x;  // 0..262143
  {
    int o = tid & 511, i = tid >> 9;
    const f32x4* src = (const f32x4*)(coeffs + (((size_t)(i * 512 + o)) << 4));
    f32x4 c0 = src[0], c1 = src[1], c2 = src[2], c3 = src[3];
    u32x4 qa, qb;
    qa[0] = pk(c0[0], c0[1]);
    qa[1] = pk(c0[2], c0[3]);
    qa[2] = pk(c1[0], c1[1]);
    qa[3] = pk(c1[2], c1[3]);
    qb[0] = pk(c2[0], c2[1]);
    qb[1] = pk(c2[2], c2[3]);
    qb[2] = pk(c3[0], c3[1]);
    qb[3] = pk(c3[2], c3[3]);
    size_t cidx = (size_t)(o >> 7) * BT_CHUNKS_PER_CT + (size_t)(2 * i) * 128 + (o & 127);
    u32x4* base = (u32x4*)bt2;
    base[cidx]       = qa;   // kslot 2i   (n=0..7)
    base[cidx + 128] = qb;   // kslot 2i+1 (n=8..15)
  }
  {
    int o2 = tid >> 9, i2 = tid & 511;
    size_t cidx = (size_t)(o2 >> 7) * BT_CHUNKS_PER_CT + (size_t)(1024 + (i2 >> 3)) * 128 + (o2 & 127);
    bt2[cidx * 8 + (i2 & 7)] = (uint16_t)bf_rtn(bw[i2 * 512 + o2]);
  }
  if (tid == 0) out[(size_t)MB_ * OD] = 0.0f;   // kl output
}

// ---------------- phase 3: fused GEMM, register-A, 16 waves -----------------
// C[8192,512] = A[8192,8704] @ B[8704,512].  Tile 128x128, BK=64.
// ROUND-11 (VALU-issue cut, r10 data paths):
//  (1) chain dedup: each lane computes ONE chain (feature fc = hiH?2+fq:fq),
//      packs 8 pairs, swaps the unused half with lane^16 via ds_swizzle.
//  (2) 2-step manual unroll -> compile-time buf, immediate-offset ds_reads,
//      running staging pointers (+const per step).
__global__ __launch_bounds__(1024, 4) void k_gemm(const float* __restrict__ t,
                                                  const uint16_t* __restrict__ xbf,
                                                  const uint16_t* __restrict__ bt2,
                                                  float* __restrict__ out) {
  __shared__ __align__(128) char lds[36864];  // B dbuf 2x16KB | t dbuf 2x2KB

  const int tid  = threadIdx.x;       // 0..1023
  const int lane = tid & 63;
  const int wid  = tid >> 6;          // 0..15
  const int wr   = wid >> 1;          // 0..7 (row group of 16)
  const int wc   = wid & 1;           // 0..1 (col group of 64)
  const int l15  = lane & 15, l4 = lane >> 4;
  const bool hiH = (l4 & 1) != 0;     // which T-half this lane's frags need
  const int fq   = l4 >> 1;           // feature sub-offset 0..1
  const int fc   = hiH ? (2 + fq) : fq;  // the ONE chain this lane computes

  // bijective XCD swizzle: each XCD gets 8 row-tiles x 4 col-tiles
  int bx  = blockIdx.x;               // 0..255
  int idx = bx >> 3;
  int rt  = (bx & 7) * 8 + (idx >> 2);   // 0..63
  int ct  = idx & 3;                     // 0..3
  const int brow = rt << 7, bcol = ct << 7;

  const char* btbase = (const char*)bt2 + (size_t)ct * BT_BYTES_PER_CT;
  const int row = brow + wr * 16 + l15;              // this lane's A row
  const uint16_t* x0 = xbf + (size_t)row * FD;

  // hoisted LDS base pointers (buf offset is a compile-time +16384/+2048)
  const char* bb0 = lds + l4 * 2048 + (wc * 64 + l15) * 16;       // B reads
  const char* tb0 = lds + 32768 + (wr * 16 + l15) * 16 + fc * 4;  // t read
  char* sBl = lds + tid * 16;                                     // B stage dst
  char* sTl = lds + 32768 + wid * 1024 + lane * 16;               // t stage dst

  // running global staging pointers
  const char* sBg = btbase + (size_t)tid * 16;                    // +16384/step
  const char* sTg = (const char*)t + (((size_t)(brow + wid * 64 + lane)) * FD) * 4; // +16/step

  f32x4 acc[4];
#pragma unroll
  for (int n = 0; n < 4; ++n) acc[n] = (f32x4)0.0f;

  u32x4 pf0 = {}, pf1 = {};           // residual prefetch regs (af[h])

  // prologue: stage B and t for step 0 into buf 0
  gload_lds16(sBg, sBl);
  sBg += 16384;
  if (wid < 2) gload_lds16(sTg, sTl);
  sTg += 16;

  auto body = [&](int step, int buf) {
    // snapshot THIS step's residual data BEFORE the next prefetch overwrites
    u32x4 af0 = pf0, af1 = pf1;

    __syncthreads();                  // buf fully staged (B + t)

    if (step < 135) {
      gload_lds16(sBg, sBl + (buf ^ 1) * 16384);
      sBg += 16384;
      if (step + 1 < 128) {
        if (wid < 2) gload_lds16(sTg, sTl + (buf ^ 1) * 2048);
        sTg += 16;
      } else {                        // prefetch xbf frags for next residual step
        int kres = ((step + 1 - 128) << 6) + l4 * 8;
        pf0 = *(const u32x4*)(x0 + kres);
        pf1 = *(const u32x4*)(x0 + kres + 32);
      }
    }

    if (step < 128) {                 // basis step: one chain + half-swap
      float tv = *(const float*)(tb0 + buf * 2048);
      float c2 = tv + tv;
      float T0 = 1.0f, T1 = tv;
      float T2  = __builtin_fmaf(c2, T1,  -T0);
      float T3  = __builtin_fmaf(c2, T2,  -T1);
      float T4  = __builtin_fmaf(c2, T3,  -T2);
      float T5  = __builtin_fmaf(c2, T4,  -T3);
      float T6  = __builtin_fmaf(c2, T5,  -T4);
      float T7  = __builtin_fmaf(c2, T6,  -T5);
      float T8  = __builtin_fmaf(c2, T7,  -T6);
      float T9  = __builtin_fmaf(c2, T8,  -T7);
      float T10 = __builtin_fmaf(c2, T9,  -T8);
      float T11 = __builtin_fmaf(c2, T10, -T9);
      float T12 = __builtin_fmaf(c2, T11, -T10);
      float T13 = __builtin_fmaf(c2, T12, -T11);
      float T14 = __builtin_fmaf(c2, T13, -T12);
      float T15 = __builtin_fmaf(c2, T14, -T13);
      uint32_t r0 = pk(T0,  T1),  r1 = pk(T2,  T3);
      uint32_t r2 = pk(T4,  T5),  r3 = pk(T6,  T7);
      uint32_t r4 = pk(T8,  T9),  r5 = pk(T10, T11);
      uint32_t r6 = pk(T12, T13), r7 = pk(T14, T15);
      // send the half I don't keep; receive partner's (lane^16, same l15/fq)
      uint32_t s0 = hiH ? r0 : r4, s1 = hiH ? r1 : r5;
      uint32_t s2 = hiH ? r2 : r6, s3 = hiH ? r3 : r7;
      uint32_t v0 = __builtin_amdgcn_ds_swizzle((int)s0, 0x401F);
      uint32_t v1 = __builtin_amdgcn_ds_swizzle((int)s1, 0x401F);
      uint32_t v2 = __builtin_amdgcn_ds_swizzle((int)s2, 0x401F);
      uint32_t v3 = __builtin_amdgcn_ds_swizzle((int)s3, 0x401F);
      // af0 = feature fq   (hiH=0: own lo; hiH=1: partner hi)
      af0[0] = hiH ? v0 : r0; af0[1] = hiH ? v1 : r1;
      af0[2] = hiH ? v2 : r2; af0[3] = hiH ? v3 : r3;
      // af1 = feature 2+fq (hiH=0: partner lo; hiH=1: own hi)
      af1[0] = hiH ? r4 : v0; af1[1] = hiH ? r5 : v1;
      af1[2] = hiH ? r6 : v2; af1[3] = hiH ? r7 : v3;
    }

    const char* bb = bb0 + buf * 16384;
    bf16x8 b00 = *(const bf16x8*)(bb);
    bf16x8 b01 = *(const bf16x8*)(bb + 256);
    bf16x8 b02 = *(const bf16x8*)(bb + 512);
    bf16x8 b03 = *(const bf16x8*)(bb + 768);
    bf16x8 b10 = *(const bf16x8*)(bb + 8192);
    bf16x8 b11 = *(const bf16x8*)(bb + 8192 + 256);
    bf16x8 b12 = *(const bf16x8*)(bb + 8192 + 512);
    bf16x8 b13 = *(const bf16x8*)(bb + 8192 + 768);
    bf16x8 a0 = *(const bf16x8*)&af0;
    bf16x8 a1 = *(const bf16x8*)&af1;
    acc[0] = __builtin_amdgcn_mfma_f32_16x16x32_bf16(a0, b00, acc[0], 0, 0, 0);
    acc[1] = __builtin_amdgcn_mfma_f32_16x16x32_bf16(a0, b01, acc[1], 0, 0, 0);
    acc[2] = __builtin_amdgcn_mfma_f32_16x16x32_bf16(a0, b02, acc[2], 0, 0, 0);
    acc[3] = __builtin_amdgcn_mfma_f32_16x16x32_bf16(a0, b03, acc[3], 0, 0, 0);
    acc[0] = __builtin_amdgcn_mfma_f32_16x16x32_bf16(a1, b10, acc[0], 0, 0, 0);
    acc[1] = __builtin_amdgcn_mfma_f32_16x16x32_bf16(a1, b11, acc[1], 0, 0, 0);
    acc[2] = __builtin_amdgcn_mfma_f32_16x16x32_bf16(a1, b12, acc[2], 0, 0, 0);
    acc[3] = __builtin_amdgcn_mfma_f32_16x16x32_bf16(a1, b13, acc[3], 0, 0, 0);
  };

  for (int s = 0; s < 136; s += 2) {  // 2-step unroll: buf compile-time
    body(s, 0);
    body(s + 1, 1);
  }

  // epilogue: C/D layout col=l&15, row=(l>>4)*4+r  [m89]
#pragma unroll
  for (int n = 0; n < 4; ++n)
#pragma unroll
    for (int r = 0; r < 4; ++r) {
      int grow = brow + wr * 16 + l4 * 4 + r;
      int gcol = bcol + wc * 64 + n * 16 + l15;
      out[(size_t)grow * OD + gcol] = acc[n][r];
    }
}

extern "C" void kernel_launch(void* const* d_in, const int* in_sizes, int n_in,
                              void* d_out, int out_size, void* d_ws, size_t ws_size,
                              hipStream_t stream) {
  const float* x      = (const float*)d_in[0];
  const float* coeffs = (const float*)d_in[1];
  const float* bw     = (const float*)d_in[2];
  float* out = (float*)d_out;
  char* ws = (char*)d_ws;

  float*    t   = (float*)ws;                                  // 16 MB fp32 tanh
  uint16_t* xbf = (uint16_t*)(ws + (size_t)16777216);          // 8 MB bf16 x
  uint16_t* bt2 = (uint16_t*)(ws + (size_t)16777216 + 8388608);// 8.5 MB tiled B

  k_tanh<<<4096, 256, 0, stream>>>(x, t, xbf);
  k_bt<<<1024, 256, 0, stream>>>(coeffs, bw, bt2, out);
  k_gemm<<<256, 1024, 0, stream>>>(t, xbf, bt2, out);
}